// Round 3
// baseline (232.921 us; speedup 1.0000x reference)
//
#include <hip/hip_runtime.h>
#include <math.h>

#define KK 64
#define CAP 64
#define NF 4160   // 64 targets x (1 self + up to 64 in-edge slots)

// Pass A: in-degree count + detect edges incident to `node`. No slot stores.
__global__ __launch_bounds__(256) void k_count(const int* __restrict__ ei, int E,
                                               const int* __restrict__ nodep,
                                               int* __restrict__ cnt,
                                               int* __restrict__ tcount,
                                               int* __restrict__ tpairs) {
    int node = nodep[0];
    int n4 = E >> 2;
    int e4 = blockIdx.x * 256 + threadIdx.x;
    if (e4 < n4) {
        int4 ss = ((const int4*)ei)[e4];
        int4 dd = ((const int4*)(ei + E))[e4];
        int s[4] = {ss.x, ss.y, ss.z, ss.w};
        int d[4] = {dd.x, dd.y, dd.z, dd.w};
#pragma unroll
        for (int k = 0; k < 4; k++) {
            atomicAdd(&cnt[d[k]], 1);
            if (s[k] == node || d[k] == node) {
                int q = atomicAdd(tcount, 1);
                if (q < KK) { int e = e4 * 4 + k; tpairs[2 * q] = e; tpairs[2 * q + 1] = (s[k] == node) ? d[k] : s[k]; }
            }
        }
    }
    // tail (E not multiple of 4)
    if (blockIdx.x == 0 && threadIdx.x == 0) {
        for (int e = n4 * 4; e < E; e++) {
            int s = ei[e], d = ei[E + e];
            atomicAdd(&cnt[d], 1);
            if (s == node || d == node) {
                int q = atomicAdd(tcount, 1);
                if (q < KK) { tpairs[2 * q] = e; tpairs[2 * q + 1] = (s == node) ? d : s; }
            }
        }
    }
}

// Sort targets by edge index (reference nonzero order); mark target flag (first owner).
__global__ void k_tsort(const int* __restrict__ tpairs, int* __restrict__ tsorted,
                        int* __restrict__ towner, int* __restrict__ tflag) {
    __shared__ int eidx[KK], tgt[KK], srt[KK];
    int t = threadIdx.x;  // 64 threads
    eidx[t] = tpairs[2 * t];
    tgt[t] = tpairs[2 * t + 1];
    __syncthreads();
    int rank = 0;
    for (int j = 0; j < KK; j++) rank += (eidx[j] < eidx[t]) ? 1 : 0;
    srt[rank] = tgt[t];
    __syncthreads();
    int mynode = srt[t];
    int owner = t;
    for (int j = 0; j < t; j++) if (srt[j] == mynode) { owner = j; break; }
    tsorted[t] = mynode;
    towner[t] = owner;
    if (owner == t) tflag[mynode] = t + 1;
}

// Pass B: collect in-edges of the 64 targets.
__global__ __launch_bounds__(256) void k_collect_t(const int* __restrict__ ei, int E,
                                                   const int* __restrict__ tflag,
                                                   int* __restrict__ tcnt2,
                                                   int* __restrict__ tslots) {
    int n4 = E >> 2;
    int e4 = blockIdx.x * 256 + threadIdx.x;
    if (e4 < n4) {
        int4 ss = ((const int4*)ei)[e4];
        int4 dd = ((const int4*)(ei + E))[e4];
        int s[4] = {ss.x, ss.y, ss.z, ss.w};
        int d[4] = {dd.x, dd.y, dd.z, dd.w};
#pragma unroll
        for (int k = 0; k < 4; k++) {
            int f = tflag[d[k]];
            if (f) { int p = atomicAdd(&tcnt2[f - 1], 1); if (p < CAP) tslots[(f - 1) * CAP + p] = s[k]; }
        }
    }
    if (blockIdx.x == 0 && threadIdx.x == 0) {
        for (int e = n4 * 4; e < E; e++) {
            int f = tflag[ei[E + e]];
            if (f) { int p = atomicAdd(&tcnt2[f - 1], 1); if (p < CAP) tslots[(f - 1) * CAP + p] = ei[e]; }
        }
    }
}

// Build frontier entries, dedup nodes (CAS owner claim), emit fidx per entry.
__global__ __launch_bounds__(1024) void k_fbuild(const int* __restrict__ tsorted,
                                                 const int* __restrict__ towner,
                                                 const int* __restrict__ tcnt2,
                                                 const int* __restrict__ tslots,
                                                 int* __restrict__ fnode,
                                                 int* __restrict__ fmapRow,
                                                 int* __restrict__ fidx) {
    int tid = threadIdx.x;
    for (int i = tid; i < NF; i += 1024) {
        int tp = i / 65, j = i % 65;
        int own = towner[tp];
        int u;
        if (j == 0) u = tsorted[tp];
        else {
            int c = tcnt2[own]; if (c > CAP) c = CAP;
            u = (j - 1 < c) ? tslots[own * CAP + (j - 1)] : -1;
        }
        fnode[i] = u;
    }
    __syncthreads();
    for (int i = tid; i < NF; i += 1024) {
        int u = fnode[i];
        if (u >= 0) atomicCAS(&fmapRow[u], 0, i + 1);
    }
    __syncthreads();
    for (int i = tid; i < NF; i += 1024) {
        int u = fnode[i];
        fidx[i] = (u >= 0) ? (fmapRow[u] - 1) : -1;
    }
}

// Pass C: collect in-edges of frontier owner rows (~67k appends).
__global__ __launch_bounds__(256) void k_collect_f(const int* __restrict__ ei, int E,
                                                   const int* __restrict__ fmapRow,
                                                   int* __restrict__ fcnt,
                                                   int* __restrict__ fslots) {
    int n4 = E >> 2;
    int e4 = blockIdx.x * 256 + threadIdx.x;
    if (e4 < n4) {
        int4 ss = ((const int4*)ei)[e4];
        int4 dd = ((const int4*)(ei + E))[e4];
        int s[4] = {ss.x, ss.y, ss.z, ss.w};
        int d[4] = {dd.x, dd.y, dd.z, dd.w};
#pragma unroll
        for (int k = 0; k < 4; k++) {
            int r = fmapRow[d[k]];
            if (r) { int p = atomicAdd(&fcnt[r - 1], 1); if (p < CAP) fslots[(size_t)(r - 1) * CAP + p] = s[k]; }
        }
    }
    if (blockIdx.x == 0 && threadIdx.x == 0) {
        for (int e = n4 * 4; e < E; e++) {
            int r = fmapRow[ei[E + e]];
            if (r) { int p = atomicAdd(&fcnt[r - 1], 1); if (p < CAP) fslots[(size_t)(r - 1) * CAP + p] = ei[e]; }
        }
    }
}

// Layer 1 fused: per owner row, gather+norm x, GEMM W1 (shfl), relu, pre-scale by dinv.
__global__ __launch_bounds__(256) void k_layer1(const float* __restrict__ x,
                                                const int* __restrict__ fnode,
                                                const int* __restrict__ fmapRow,
                                                const int* __restrict__ cnt,
                                                const int* __restrict__ fcnt,
                                                const int* __restrict__ fslots,
                                                const float* __restrict__ W1,
                                                const float* __restrict__ b1,
                                                float* __restrict__ h1s) {
    __shared__ __align__(16) float W1s[64 * 64];
    int tid = threadIdx.x;
    for (int i = tid; i < 1024; i += 256) ((float4*)W1s)[i] = ((const float4*)W1)[i];
    __syncthreads();
    int i = blockIdx.x * 4 + (tid >> 6);
    int lane = tid & 63;
    if (i >= NF) return;
    int u = fnode[i];
    if (u < 0 || fmapRow[u] != i + 1) return;   // invalid or duplicate (non-owner)
    float du = rsqrtf((float)(cnt[u] + 1));
    float acc = du * x[(size_t)u * 64 + lane];
    int c = fcnt[i]; if (c > CAP) c = CAP;
    const int* sl = fslots + (size_t)i * CAP;
    int k = 0;
    for (; k + 4 <= c; k += 4) {
        int u0 = sl[k], u1 = sl[k + 1], u2 = sl[k + 2], u3 = sl[k + 3];
        float f0 = rsqrtf((float)(cnt[u0] + 1));
        float f1 = rsqrtf((float)(cnt[u1] + 1));
        float f2 = rsqrtf((float)(cnt[u2] + 1));
        float f3 = rsqrtf((float)(cnt[u3] + 1));
        acc += f0 * x[(size_t)u0 * 64 + lane] + f1 * x[(size_t)u1 * 64 + lane]
             + f2 * x[(size_t)u2 * 64 + lane] + f3 * x[(size_t)u3 * 64 + lane];
    }
    for (; k < c; k++) {
        int uu = sl[k];
        acc += rsqrtf((float)(cnt[uu] + 1)) * x[(size_t)uu * 64 + lane];
    }
    float z = du * acc;
    float h = 0.f;
#pragma unroll
    for (int f = 0; f < 64; f++) h += __shfl(z, f) * W1s[f * 64 + lane];
    h = fmaxf(h + b1[lane], 0.f);
    h1s[(size_t)i * 64 + lane] = du * h;
}

// Layer 2 + score + softmax. One block, 16 waves, wave-per-target.
__global__ __launch_bounds__(1024) void k_score(const float* __restrict__ h1s,
                                                const int* __restrict__ fidx,
                                                const int* __restrict__ tsorted,
                                                const int* __restrict__ cnt,
                                                const float* __restrict__ W2,
                                                const float* __restrict__ b2,
                                                const float* __restrict__ Wr,
                                                const float* __restrict__ br,
                                                float* __restrict__ out) {
    __shared__ __align__(16) float W2s[64 * 64];
    __shared__ float sc[KK];
    int tid = threadIdx.x;
    ((float4*)W2s)[tid] = ((const float4*)W2)[tid];
    __syncthreads();
    int wave = tid >> 6, lane = tid & 63;
    float wr = Wr[lane];
    float bb = b2[lane];
    for (int tp = wave; tp < KK; tp += 16) {
        int t = tsorted[tp];
        float dt = rsqrtf((float)(cnt[t] + 1));
        float z = 0.f;
        const int* fx = fidx + tp * 65;
#pragma unroll 4
        for (int j = 0; j < 65; j++) {
            int idx = fx[j];
            if (idx >= 0) z += h1s[(size_t)idx * 64 + lane];
        }
        z *= dt;
        float acc = 0.f;
#pragma unroll
        for (int f = 0; f < 64; f++) acc += __shfl(z, f) * W2s[f * 64 + lane];
        float h2 = fmaxf(acc + bb, 0.f);
        float p = h2 * wr;
#pragma unroll
        for (int off = 32; off >= 1; off >>= 1) p += __shfl_xor(p, off);
        if (lane == 0) sc[tp] = p + br[0];
    }
    __syncthreads();
    if (tid < KK) {
        float s = sc[tid];
        float m = s;
#pragma unroll
        for (int off = 32; off >= 1; off >>= 1) m = fmaxf(m, __shfl_xor(m, off));
        float e = __expf(s - m);
        float ss = e;
#pragma unroll
        for (int off = 32; off >= 1; off >>= 1) ss += __shfl_xor(ss, off);
        out[tid] = e / ss;
        out[KK + tid] = (float)tsorted[tid];
    }
}

extern "C" void kernel_launch(void* const* d_in, const int* in_sizes, int n_in,
                              void* d_out, int out_size, void* d_ws, size_t ws_size,
                              hipStream_t stream) {
    const float* x  = (const float*)d_in[0];
    const int*   ei = (const int*)d_in[1];
    const int*   nodep = (const int*)d_in[2];
    const float* W1 = (const float*)d_in[3];
    const float* b1 = (const float*)d_in[4];
    const float* W2 = (const float*)d_in[5];
    const float* b2 = (const float*)d_in[6];
    const float* Wr = (const float*)d_in[7];
    const float* br = (const float*)d_in[8];
    float* out = (float*)d_out;

    int N = in_sizes[0] / 64;   // 50000
    int E = in_sizes[1] / 2;    // 800064

    char* w = (char*)d_ws;
    // ---- zeroed region (one memset) ----
    int* cnt     = (int*)w; w += (size_t)N * 4;          // in-degrees
    int* tflag   = (int*)w; w += (size_t)N * 4;          // node -> target slot+1
    int* fmapRow = (int*)w; w += (size_t)N * 4;          // node -> frontier owner entry+1
    int* fcnt    = (int*)w; w += (size_t)NF * 4;
    int* tcnt2   = (int*)w; w += KK * 4;
    int* tcount  = (int*)w; w += 16;
    size_t zbytes = (size_t)(3 * N + NF + KK) * 4 + 16;
    // ---- non-zeroed ----
    int* tpairs  = (int*)w; w += 2 * KK * 4;
    int* tsorted = (int*)w; w += KK * 4;
    int* towner  = (int*)w; w += KK * 4;
    int* fnode   = (int*)w; w += (size_t)NF * 4;
    int* fidx    = (int*)w; w += (size_t)NF * 4;
    int* tslots  = (int*)w; w += (size_t)KK * CAP * 4;
    int* fslots  = (int*)w; w += (size_t)NF * CAP * 4;   // ~1.06 MB
    float* h1s   = (float*)w; w += (size_t)NF * 64 * 4;  // ~1.06 MB

    hipMemsetAsync(cnt, 0, zbytes, stream);

    int ebl = (E / 4 + 255) / 256;
    k_count<<<ebl, 256, 0, stream>>>(ei, E, nodep, cnt, tcount, tpairs);
    k_tsort<<<1, 64, 0, stream>>>(tpairs, tsorted, towner, tflag);
    k_collect_t<<<ebl, 256, 0, stream>>>(ei, E, tflag, tcnt2, tslots);
    k_fbuild<<<1, 1024, 0, stream>>>(tsorted, towner, tcnt2, tslots, fnode, fmapRow, fidx);
    k_collect_f<<<ebl, 256, 0, stream>>>(ei, E, fmapRow, fcnt, fslots);
    k_layer1<<<(NF + 3) / 4, 256, 0, stream>>>(x, fnode, fmapRow, cnt, fcnt, fslots, W1, b1, h1s);
    k_score<<<1, 1024, 0, stream>>>(h1s, fidx, tsorted, cnt, W2, b2, Wr, br, out);
}

// Round 4
// 173.204 us; speedup vs baseline: 1.3448x; 1.3448x over previous
//
#include <hip/hip_runtime.h>
#include <math.h>

#define KK 64
#define CAP 64
#define NF 4160   // 64 targets x (1 self + up to 64 in-edge slots)

// Pass A: in-degree count + detect edges incident to `node`. No slot stores.
__global__ __launch_bounds__(256) void k_count(const int* __restrict__ ei, int E,
                                               const int* __restrict__ nodep,
                                               int* __restrict__ cnt,
                                               int* __restrict__ tcount,
                                               int* __restrict__ tpairs) {
    int node = nodep[0];
    int n4 = E >> 2;
    int e4 = blockIdx.x * 256 + threadIdx.x;
    if (e4 < n4) {
        int4 ss = ((const int4*)ei)[e4];
        int4 dd = ((const int4*)(ei + E))[e4];
        int s[4] = {ss.x, ss.y, ss.z, ss.w};
        int d[4] = {dd.x, dd.y, dd.z, dd.w};
#pragma unroll
        for (int k = 0; k < 4; k++) {
            atomicAdd(&cnt[d[k]], 1);
            if (s[k] == node || d[k] == node) {
                int q = atomicAdd(tcount, 1);
                if (q < KK) { int e = e4 * 4 + k; tpairs[2 * q] = e; tpairs[2 * q + 1] = (s[k] == node) ? d[k] : s[k]; }
            }
        }
    }
    if (blockIdx.x == 0 && threadIdx.x == 0) {
        for (int e = n4 * 4; e < E; e++) {
            int s = ei[e], d = ei[E + e];
            atomicAdd(&cnt[d], 1);
            if (s == node || d == node) {
                int q = atomicAdd(tcount, 1);
                if (q < KK) { tpairs[2 * q] = e; tpairs[2 * q + 1] = (s == node) ? d : s; }
            }
        }
    }
}

// Sort targets by edge index (reference nonzero order); mark target flag (first owner).
// Also zeroes the dedicated zero-row (row NF) of h1s.
__global__ void k_tsort(const int* __restrict__ tpairs, int* __restrict__ tsorted,
                        int* __restrict__ towner, int* __restrict__ tflag,
                        float* __restrict__ h1s) {
    __shared__ int eidx[KK], tgt[KK], srt[KK];
    int t = threadIdx.x;  // 64 threads
    h1s[(size_t)NF * 64 + t] = 0.f;
    eidx[t] = tpairs[2 * t];
    tgt[t] = tpairs[2 * t + 1];
    __syncthreads();
    int rank = 0;
    for (int j = 0; j < KK; j++) rank += (eidx[j] < eidx[t]) ? 1 : 0;
    srt[rank] = tgt[t];
    __syncthreads();
    int mynode = srt[t];
    int owner = t;
    for (int j = 0; j < t; j++) if (srt[j] == mynode) { owner = j; break; }
    tsorted[t] = mynode;
    towner[t] = owner;
    if (owner == t) tflag[mynode] = t + 1;
}

// Pass B: collect in-edges of the 64 targets.
__global__ __launch_bounds__(256) void k_collect_t(const int* __restrict__ ei, int E,
                                                   const int* __restrict__ tflag,
                                                   int* __restrict__ tcnt2,
                                                   int* __restrict__ tslots) {
    int n4 = E >> 2;
    int e4 = blockIdx.x * 256 + threadIdx.x;
    if (e4 < n4) {
        int4 ss = ((const int4*)ei)[e4];
        int4 dd = ((const int4*)(ei + E))[e4];
        int s[4] = {ss.x, ss.y, ss.z, ss.w};
        int d[4] = {dd.x, dd.y, dd.z, dd.w};
#pragma unroll
        for (int k = 0; k < 4; k++) {
            int f = tflag[d[k]];
            if (f) { int p = atomicAdd(&tcnt2[f - 1], 1); if (p < CAP) tslots[(f - 1) * CAP + p] = s[k]; }
        }
    }
    if (blockIdx.x == 0 && threadIdx.x == 0) {
        for (int e = n4 * 4; e < E; e++) {
            int f = tflag[ei[E + e]];
            if (f) { int p = atomicAdd(&tcnt2[f - 1], 1); if (p < CAP) tslots[(f - 1) * CAP + p] = ei[e]; }
        }
    }
}

// Build frontier entries, dedup nodes (CAS owner claim), emit fidx per entry.
// Pad entries get fidx = NF (the zero row) so downstream loads are branchless.
__global__ __launch_bounds__(1024) void k_fbuild(const int* __restrict__ tsorted,
                                                 const int* __restrict__ towner,
                                                 const int* __restrict__ tcnt2,
                                                 const int* __restrict__ tslots,
                                                 int* __restrict__ fnode,
                                                 int* __restrict__ fmapRow,
                                                 int* __restrict__ fidx) {
    int tid = threadIdx.x;
    for (int i = tid; i < NF; i += 1024) {
        int tp = i / 65, j = i % 65;
        int own = towner[tp];
        int u;
        if (j == 0) u = tsorted[tp];
        else {
            int c = tcnt2[own]; if (c > CAP) c = CAP;
            u = (j - 1 < c) ? tslots[own * CAP + (j - 1)] : -1;
        }
        fnode[i] = u;
    }
    __syncthreads();
    for (int i = tid; i < NF; i += 1024) {
        int u = fnode[i];
        if (u >= 0) atomicCAS(&fmapRow[u], 0, i + 1);
    }
    __syncthreads();
    for (int i = tid; i < NF; i += 1024) {
        int u = fnode[i];
        fidx[i] = (u >= 0) ? (fmapRow[u] - 1) : NF;
    }
}

// Pass C: collect in-edges of frontier owner rows (~67k appends).
__global__ __launch_bounds__(256) void k_collect_f(const int* __restrict__ ei, int E,
                                                   const int* __restrict__ fmapRow,
                                                   int* __restrict__ fcnt,
                                                   int* __restrict__ fslots) {
    int n4 = E >> 2;
    int e4 = blockIdx.x * 256 + threadIdx.x;
    if (e4 < n4) {
        int4 ss = ((const int4*)ei)[e4];
        int4 dd = ((const int4*)(ei + E))[e4];
        int s[4] = {ss.x, ss.y, ss.z, ss.w};
        int d[4] = {dd.x, dd.y, dd.z, dd.w};
#pragma unroll
        for (int k = 0; k < 4; k++) {
            int r = fmapRow[d[k]];
            if (r) { int p = atomicAdd(&fcnt[r - 1], 1); if (p < CAP) fslots[(size_t)(r - 1) * CAP + p] = s[k]; }
        }
    }
    if (blockIdx.x == 0 && threadIdx.x == 0) {
        for (int e = n4 * 4; e < E; e++) {
            int r = fmapRow[ei[E + e]];
            if (r) { int p = atomicAdd(&fcnt[r - 1], 1); if (p < CAP) fslots[(size_t)(r - 1) * CAP + p] = ei[e]; }
        }
    }
}

// Layer 1 fused: per owner row, gather+norm x, GEMM W1 (shfl), relu, pre-scale by dinv.
__global__ __launch_bounds__(256) void k_layer1(const float* __restrict__ x,
                                                const int* __restrict__ fnode,
                                                const int* __restrict__ fmapRow,
                                                const int* __restrict__ cnt,
                                                const int* __restrict__ fcnt,
                                                const int* __restrict__ fslots,
                                                const float* __restrict__ W1,
                                                const float* __restrict__ b1,
                                                float* __restrict__ h1s) {
    __shared__ __align__(16) float W1s[64 * 64];
    int tid = threadIdx.x;
    for (int i = tid; i < 1024; i += 256) ((float4*)W1s)[i] = ((const float4*)W1)[i];
    __syncthreads();
    int i = blockIdx.x * 4 + (tid >> 6);
    int lane = tid & 63;
    if (i >= NF) return;
    int u = fnode[i];
    if (u < 0 || fmapRow[u] != i + 1) return;   // invalid or duplicate (non-owner)
    float du = rsqrtf((float)(cnt[u] + 1));
    float acc = du * x[(size_t)u * 64 + lane];
    int c = fcnt[i]; if (c > CAP) c = CAP;
    const int* sl = fslots + (size_t)i * CAP;
    int k = 0;
    for (; k + 4 <= c; k += 4) {
        int u0 = sl[k], u1 = sl[k + 1], u2 = sl[k + 2], u3 = sl[k + 3];
        float f0 = rsqrtf((float)(cnt[u0] + 1));
        float f1 = rsqrtf((float)(cnt[u1] + 1));
        float f2 = rsqrtf((float)(cnt[u2] + 1));
        float f3 = rsqrtf((float)(cnt[u3] + 1));
        acc += f0 * x[(size_t)u0 * 64 + lane] + f1 * x[(size_t)u1 * 64 + lane]
             + f2 * x[(size_t)u2 * 64 + lane] + f3 * x[(size_t)u3 * 64 + lane];
    }
    for (; k < c; k++) {
        int uu = sl[k];
        acc += rsqrtf((float)(cnt[uu] + 1)) * x[(size_t)uu * 64 + lane];
    }
    float z = du * acc;
    float h = 0.f;
#pragma unroll
    for (int f = 0; f < 64; f++) h += __shfl(z, f) * W1s[f * 64 + lane];
    h = fmaxf(h + b1[lane], 0.f);
    h1s[(size_t)i * 64 + lane] = du * h;
}

// Layer 2 + raw score. One block per target, one wave. Branchless 65-row sum
// (pads point at the zero row NF), then shfl-GEMM with W2 from global (L2-hot).
__global__ __launch_bounds__(64) void k_score2(const float* __restrict__ h1s,
                                               const int* __restrict__ fidx,
                                               const int* __restrict__ tsorted,
                                               const int* __restrict__ cnt,
                                               const float* __restrict__ W2,
                                               const float* __restrict__ b2,
                                               const float* __restrict__ Wr,
                                               float* __restrict__ sc) {
    int tp = blockIdx.x;
    int lane = threadIdx.x;
    int t = tsorted[tp];
    float dt = rsqrtf((float)(cnt[t] + 1));
    const int* fx = fidx + tp * 65;
    float z = 0.f;
#pragma unroll
    for (int j = 0; j < 65; j++) {
        int idx = fx[j];                      // wave-uniform -> scalar load
        z += h1s[(size_t)idx * 64 + lane];    // unconditional, independent
    }
    z *= dt;
    float acc = 0.f;
#pragma unroll
    for (int f = 0; f < 64; f++) acc += __shfl(z, f) * W2[f * 64 + lane];
    float h2 = fmaxf(acc + b2[lane], 0.f);
    float p = h2 * Wr[lane];
#pragma unroll
    for (int off = 32; off >= 1; off >>= 1) p += __shfl_xor(p, off);
    if (lane == 0) sc[tp] = p;   // br omitted: constant shift cancels in softmax
}

__global__ void k_softmax(const float* __restrict__ sc, const int* __restrict__ tsorted,
                          float* __restrict__ out) {
    int t = threadIdx.x;  // 64 threads
    float s = sc[t];
    float m = s;
#pragma unroll
    for (int off = 32; off >= 1; off >>= 1) m = fmaxf(m, __shfl_xor(m, off));
    float e = __expf(s - m);
    float ss = e;
#pragma unroll
    for (int off = 32; off >= 1; off >>= 1) ss += __shfl_xor(ss, off);
    out[t] = e / ss;
    out[KK + t] = (float)tsorted[t];
}

extern "C" void kernel_launch(void* const* d_in, const int* in_sizes, int n_in,
                              void* d_out, int out_size, void* d_ws, size_t ws_size,
                              hipStream_t stream) {
    const float* x  = (const float*)d_in[0];
    const int*   ei = (const int*)d_in[1];
    const int*   nodep = (const int*)d_in[2];
    const float* W1 = (const float*)d_in[3];
    const float* b1 = (const float*)d_in[4];
    const float* W2 = (const float*)d_in[5];
    const float* b2 = (const float*)d_in[6];
    const float* Wr = (const float*)d_in[7];
    const float* br = (const float*)d_in[8];
    float* out = (float*)d_out;
    (void)br;

    int N = in_sizes[0] / 64;   // 50000
    int E = in_sizes[1] / 2;    // 800064

    char* w = (char*)d_ws;
    // ---- zeroed region (one memset) ----
    int* cnt     = (int*)w; w += (size_t)N * 4;          // in-degrees
    int* tflag   = (int*)w; w += (size_t)N * 4;          // node -> target slot+1
    int* fmapRow = (int*)w; w += (size_t)N * 4;          // node -> frontier owner entry+1
    int* fcnt    = (int*)w; w += (size_t)NF * 4;
    int* tcnt2   = (int*)w; w += KK * 4;
    int* tcount  = (int*)w; w += 16;
    size_t zbytes = (size_t)(3 * N + NF + KK) * 4 + 16;
    // ---- non-zeroed ----
    int* tpairs  = (int*)w; w += 2 * KK * 4;
    int* tsorted = (int*)w; w += KK * 4;
    int* towner  = (int*)w; w += KK * 4;
    int* fnode   = (int*)w; w += (size_t)NF * 4;
    int* fidx    = (int*)w; w += (size_t)NF * 4;
    int* tslots  = (int*)w; w += (size_t)KK * CAP * 4;
    int* fslots  = (int*)w; w += (size_t)NF * CAP * 4;       // ~1.06 MB
    float* h1s   = (float*)w; w += (size_t)(NF + 1) * 64 * 4; // +1 zero row
    float* sc    = (float*)w; w += KK * 4;

    hipMemsetAsync(cnt, 0, zbytes, stream);

    int ebl = (E / 4 + 255) / 256;
    k_count<<<ebl, 256, 0, stream>>>(ei, E, nodep, cnt, tcount, tpairs);
    k_tsort<<<1, 64, 0, stream>>>(tpairs, tsorted, towner, tflag, h1s);
    k_collect_t<<<ebl, 256, 0, stream>>>(ei, E, tflag, tcnt2, tslots);
    k_fbuild<<<1, 1024, 0, stream>>>(tsorted, towner, tcnt2, tslots, fnode, fmapRow, fidx);
    k_collect_f<<<ebl, 256, 0, stream>>>(ei, E, fmapRow, fcnt, fslots);
    k_layer1<<<(NF + 3) / 4, 256, 0, stream>>>(x, fnode, fmapRow, cnt, fcnt, fslots, W1, b1, h1s);
    k_score2<<<KK, 64, 0, stream>>>(h1s, fidx, tsorted, cnt, W2, b2, Wr, sc);
    k_softmax<<<1, 64, 0, stream>>>(sc, tsorted, out);
}

// Round 5
// 171.476 us; speedup vs baseline: 1.3583x; 1.0101x over previous
//
#include <hip/hip_runtime.h>
#include <math.h>

#define KK 64
#define CAP 64
#define NF 4160   // 64 targets x (1 self + up to 64 in-edge slots)

// Pass 1 (read-only scan): detect edges incident to `node`; also zero the
// workspace region (cnt/tflag/fmapRow/fcnt/tcnt2) and the h1s zero-row.
// All zeroed arrays are consumed only by LATER kernels, so no intra-kernel
// ordering is needed. tcount itself is zeroed by the preceding 16B memset.
__global__ __launch_bounds__(256) void k_find(const int* __restrict__ ei, int E,
                                              const int* __restrict__ nodep,
                                              int4* __restrict__ zbase, int zcount4,
                                              float* __restrict__ h1s,
                                              int* __restrict__ tcount,
                                              int* __restrict__ tpairs) {
    int idx = blockIdx.x * 256 + threadIdx.x;
    if (idx < zcount4) zbase[idx] = make_int4(0, 0, 0, 0);
    if (idx < 64) h1s[(size_t)NF * 64 + idx] = 0.f;
    int node = nodep[0];
    int n4 = E >> 2;
    if (idx < n4) {
        int4 ss = ((const int4*)ei)[idx];
        int4 dd = ((const int4*)(ei + E))[idx];
        int s[4] = {ss.x, ss.y, ss.z, ss.w};
        int d[4] = {dd.x, dd.y, dd.z, dd.w};
#pragma unroll
        for (int k = 0; k < 4; k++) {
            if (s[k] == node || d[k] == node) {
                int q = atomicAdd(tcount, 1);
                if (q < KK) { int e = idx * 4 + k; tpairs[2 * q] = e; tpairs[2 * q + 1] = (s[k] == node) ? d[k] : s[k]; }
            }
        }
    }
    if (idx == 0) {
        for (int e = n4 * 4; e < E; e++) {
            int s = ei[e], d = ei[E + e];
            if (s == node || d == node) {
                int q = atomicAdd(tcount, 1);
                if (q < KK) { tpairs[2 * q] = e; tpairs[2 * q + 1] = (s == node) ? d : s; }
            }
        }
    }
}

// Sort targets by edge index (reference nonzero order); mark target flag (first owner).
__global__ void k_tsort(const int* __restrict__ tpairs, int* __restrict__ tsorted,
                        int* __restrict__ towner, int* __restrict__ tflag) {
    __shared__ int eidx[KK], tgt[KK], srt[KK];
    int t = threadIdx.x;  // 64 threads
    eidx[t] = tpairs[2 * t];
    tgt[t] = tpairs[2 * t + 1];
    __syncthreads();
    int rank = 0;
    for (int j = 0; j < KK; j++) rank += (eidx[j] < eidx[t]) ? 1 : 0;
    srt[rank] = tgt[t];
    __syncthreads();
    int mynode = srt[t];
    int owner = t;
    for (int j = 0; j < t; j++) if (srt[j] == mynode) { owner = j; break; }
    tsorted[t] = mynode;
    towner[t] = owner;
    if (owner == t) tflag[mynode] = t + 1;
}

// Pass 2 (fused): in-degree count for ALL nodes + collect in-edges of targets.
__global__ __launch_bounds__(256) void k_cct(const int* __restrict__ ei, int E,
                                             const int* __restrict__ tflag,
                                             int* __restrict__ cnt,
                                             int* __restrict__ tcnt2,
                                             int* __restrict__ tslots) {
    int n4 = E >> 2;
    int e4 = blockIdx.x * 256 + threadIdx.x;
    if (e4 < n4) {
        int4 ss = ((const int4*)ei)[e4];
        int4 dd = ((const int4*)(ei + E))[e4];
        int s[4] = {ss.x, ss.y, ss.z, ss.w};
        int d[4] = {dd.x, dd.y, dd.z, dd.w};
#pragma unroll
        for (int k = 0; k < 4; k++) {
            atomicAdd(&cnt[d[k]], 1);
            int f = tflag[d[k]];
            if (f) { int p = atomicAdd(&tcnt2[f - 1], 1); if (p < CAP) tslots[(f - 1) * CAP + p] = s[k]; }
        }
    }
    if (blockIdx.x == 0 && threadIdx.x == 0) {
        for (int e = n4 * 4; e < E; e++) {
            int d = ei[E + e];
            atomicAdd(&cnt[d], 1);
            int f = tflag[d];
            if (f) { int p = atomicAdd(&tcnt2[f - 1], 1); if (p < CAP) tslots[(f - 1) * CAP + p] = ei[e]; }
        }
    }
}

// Build frontier entries, dedup nodes (CAS owner claim), emit fidx per entry.
// Pad entries get fidx = NF (the zero row) so downstream loads are branchless.
__global__ __launch_bounds__(1024) void k_fbuild(const int* __restrict__ tsorted,
                                                 const int* __restrict__ towner,
                                                 const int* __restrict__ tcnt2,
                                                 const int* __restrict__ tslots,
                                                 int* __restrict__ fnode,
                                                 int* __restrict__ fmapRow,
                                                 int* __restrict__ fidx) {
    int tid = threadIdx.x;
    for (int i = tid; i < NF; i += 1024) {
        int tp = i / 65, j = i % 65;
        int own = towner[tp];
        int u;
        if (j == 0) u = tsorted[tp];
        else {
            int c = tcnt2[own]; if (c > CAP) c = CAP;
            u = (j - 1 < c) ? tslots[own * CAP + (j - 1)] : -1;
        }
        fnode[i] = u;
    }
    __syncthreads();
    for (int i = tid; i < NF; i += 1024) {
        int u = fnode[i];
        if (u >= 0) atomicCAS(&fmapRow[u], 0, i + 1);
    }
    __syncthreads();
    for (int i = tid; i < NF; i += 1024) {
        int u = fnode[i];
        fidx[i] = (u >= 0) ? (fmapRow[u] - 1) : NF;
    }
}

// Pass 3: collect in-edges of frontier owner rows (~67k appends).
__global__ __launch_bounds__(256) void k_collect_f(const int* __restrict__ ei, int E,
                                                   const int* __restrict__ fmapRow,
                                                   int* __restrict__ fcnt,
                                                   int* __restrict__ fslots) {
    int n4 = E >> 2;
    int e4 = blockIdx.x * 256 + threadIdx.x;
    if (e4 < n4) {
        int4 ss = ((const int4*)ei)[e4];
        int4 dd = ((const int4*)(ei + E))[e4];
        int s[4] = {ss.x, ss.y, ss.z, ss.w};
        int d[4] = {dd.x, dd.y, dd.z, dd.w};
#pragma unroll
        for (int k = 0; k < 4; k++) {
            int r = fmapRow[d[k]];
            if (r) { int p = atomicAdd(&fcnt[r - 1], 1); if (p < CAP) fslots[(size_t)(r - 1) * CAP + p] = s[k]; }
        }
    }
    if (blockIdx.x == 0 && threadIdx.x == 0) {
        for (int e = n4 * 4; e < E; e++) {
            int r = fmapRow[ei[E + e]];
            if (r) { int p = atomicAdd(&fcnt[r - 1], 1); if (p < CAP) fslots[(size_t)(r - 1) * CAP + p] = ei[e]; }
        }
    }
}

// Layer 1 fused: per owner row, gather+norm x, GEMM W1 (shfl), relu, pre-scale by dinv.
__global__ __launch_bounds__(256) void k_layer1(const float* __restrict__ x,
                                                const int* __restrict__ fnode,
                                                const int* __restrict__ fmapRow,
                                                const int* __restrict__ cnt,
                                                const int* __restrict__ fcnt,
                                                const int* __restrict__ fslots,
                                                const float* __restrict__ W1,
                                                const float* __restrict__ b1,
                                                float* __restrict__ h1s) {
    __shared__ __align__(16) float W1s[64 * 64];
    int tid = threadIdx.x;
    for (int i = tid; i < 1024; i += 256) ((float4*)W1s)[i] = ((const float4*)W1)[i];
    __syncthreads();
    int i = blockIdx.x * 4 + (tid >> 6);
    int lane = tid & 63;
    if (i >= NF) return;
    int u = fnode[i];
    if (u < 0 || fmapRow[u] != i + 1) return;   // invalid or duplicate (non-owner)
    float du = rsqrtf((float)(cnt[u] + 1));
    float acc = du * x[(size_t)u * 64 + lane];
    int c = fcnt[i]; if (c > CAP) c = CAP;
    const int* sl = fslots + (size_t)i * CAP;
    int k = 0;
    for (; k + 4 <= c; k += 4) {
        int u0 = sl[k], u1 = sl[k + 1], u2 = sl[k + 2], u3 = sl[k + 3];
        float f0 = rsqrtf((float)(cnt[u0] + 1));
        float f1 = rsqrtf((float)(cnt[u1] + 1));
        float f2 = rsqrtf((float)(cnt[u2] + 1));
        float f3 = rsqrtf((float)(cnt[u3] + 1));
        acc += f0 * x[(size_t)u0 * 64 + lane] + f1 * x[(size_t)u1 * 64 + lane]
             + f2 * x[(size_t)u2 * 64 + lane] + f3 * x[(size_t)u3 * 64 + lane];
    }
    for (; k < c; k++) {
        int uu = sl[k];
        acc += rsqrtf((float)(cnt[uu] + 1)) * x[(size_t)uu * 64 + lane];
    }
    float z = du * acc;
    float h = 0.f;
#pragma unroll
    for (int f = 0; f < 64; f++) h += __shfl(z, f) * W1s[f * 64 + lane];
    h = fmaxf(h + b1[lane], 0.f);
    h1s[(size_t)i * 64 + lane] = du * h;
}

// Layer 2 + raw score. One block per target, one wave. Branchless 65-row sum
// (pads point at the zero row NF), then shfl-GEMM with W2 from global (L2-hot).
__global__ __launch_bounds__(64) void k_score2(const float* __restrict__ h1s,
                                               const int* __restrict__ fidx,
                                               const int* __restrict__ tsorted,
                                               const int* __restrict__ cnt,
                                               const float* __restrict__ W2,
                                               const float* __restrict__ b2,
                                               const float* __restrict__ Wr,
                                               float* __restrict__ sc) {
    int tp = blockIdx.x;
    int lane = threadIdx.x;
    int t = tsorted[tp];
    float dt = rsqrtf((float)(cnt[t] + 1));
    const int* fx = fidx + tp * 65;
    float z = 0.f;
#pragma unroll
    for (int j = 0; j < 65; j++) {
        int idx = fx[j];                      // wave-uniform -> scalar load
        z += h1s[(size_t)idx * 64 + lane];    // unconditional, independent
    }
    z *= dt;
    float acc = 0.f;
#pragma unroll
    for (int f = 0; f < 64; f++) acc += __shfl(z, f) * W2[f * 64 + lane];
    float h2 = fmaxf(acc + b2[lane], 0.f);
    float p = h2 * Wr[lane];
#pragma unroll
    for (int off = 32; off >= 1; off >>= 1) p += __shfl_xor(p, off);
    if (lane == 0) sc[tp] = p;   // br omitted: constant shift cancels in softmax
}

__global__ void k_softmax(const float* __restrict__ sc, const int* __restrict__ tsorted,
                          float* __restrict__ out) {
    int t = threadIdx.x;  // 64 threads
    float s = sc[t];
    float m = s;
#pragma unroll
    for (int off = 32; off >= 1; off >>= 1) m = fmaxf(m, __shfl_xor(m, off));
    float e = __expf(s - m);
    float ss = e;
#pragma unroll
    for (int off = 32; off >= 1; off >>= 1) ss += __shfl_xor(ss, off);
    out[t] = e / ss;
    out[KK + t] = (float)tsorted[t];
}

extern "C" void kernel_launch(void* const* d_in, const int* in_sizes, int n_in,
                              void* d_out, int out_size, void* d_ws, size_t ws_size,
                              hipStream_t stream) {
    const float* x  = (const float*)d_in[0];
    const int*   ei = (const int*)d_in[1];
    const int*   nodep = (const int*)d_in[2];
    const float* W1 = (const float*)d_in[3];
    const float* b1 = (const float*)d_in[4];
    const float* W2 = (const float*)d_in[5];
    const float* b2 = (const float*)d_in[6];
    const float* Wr = (const float*)d_in[7];
    const float* br = (const float*)d_in[8];
    float* out = (float*)d_out;
    (void)br;

    int N = in_sizes[0] / 64;   // 50000
    int E = in_sizes[1] / 2;    // 800064

    char* w = (char*)d_ws;
    // ---- region zeroed inside k_find (contiguous, int4-aligned) ----
    int* cnt     = (int*)w; w += (size_t)N * 4;          // in-degrees
    int* tflag   = (int*)w; w += (size_t)N * 4;          // node -> target slot+1
    int* fmapRow = (int*)w; w += (size_t)N * 4;          // node -> frontier owner entry+1
    int* fcnt    = (int*)w; w += (size_t)NF * 4;
    int* tcnt2   = (int*)w; w += KK * 4;
    int zcount4 = (3 * N + NF + KK) / 4;                 // 154224 ints -> 38556 int4
    // ---- zeroed by the 16B memset (used by k_find itself) ----
    int* tcount  = (int*)w; w += 16;
    // ---- non-zeroed ----
    int* tpairs  = (int*)w; w += 2 * KK * 4;
    int* tsorted = (int*)w; w += KK * 4;
    int* towner  = (int*)w; w += KK * 4;
    int* fnode   = (int*)w; w += (size_t)NF * 4;
    int* fidx    = (int*)w; w += (size_t)NF * 4;
    int* tslots  = (int*)w; w += (size_t)KK * CAP * 4;
    int* fslots  = (int*)w; w += (size_t)NF * CAP * 4;       // ~1.06 MB
    float* h1s   = (float*)w; w += (size_t)(NF + 1) * 64 * 4; // +1 zero row
    float* sc    = (float*)w; w += KK * 4;

    hipMemsetAsync(tcount, 0, 16, stream);

    int ebl = (E / 4 + 255) / 256;   // covers both edge scan and zeroing range
    k_find<<<ebl, 256, 0, stream>>>(ei, E, nodep, (int4*)cnt, zcount4, h1s, tcount, tpairs);
    k_tsort<<<1, 64, 0, stream>>>(tpairs, tsorted, towner, tflag);
    k_cct<<<ebl, 256, 0, stream>>>(ei, E, tflag, cnt, tcnt2, tslots);
    k_fbuild<<<1, 1024, 0, stream>>>(tsorted, towner, tcnt2, tslots, fnode, fmapRow, fidx);
    k_collect_f<<<ebl, 256, 0, stream>>>(ei, E, fmapRow, fcnt, fslots);
    k_layer1<<<(NF + 3) / 4, 256, 0, stream>>>(x, fnode, fmapRow, cnt, fcnt, fslots, W1, b1, h1s);
    k_score2<<<KK, 64, 0, stream>>>(h1s, fidx, tsorted, cnt, W2, b2, Wr, sc);
    k_softmax<<<1, 64, 0, stream>>>(sc, tsorted, out);
}